// Round 1
// 483.455 us; speedup vs baseline: 1.0085x; 1.0085x over previous
//
#include <hip/hip_runtime.h>
#include <cmath>

#define NPOS 16384
#define ATT_SCALE 0.125f

typedef float f4 __attribute__((ext_vector_type(4)));
typedef short short8 __attribute__((ext_vector_type(8)));
typedef unsigned int uint;
typedef unsigned short ushort;

__device__ __forceinline__ ushort f2bf(float f) {
    union { float f; uint u; } v; v.f = f;
    uint r = v.u + 0x7fffu + ((v.u >> 16) & 1u);
    return (ushort)(r >> 16);
}
__device__ __forceinline__ float bfl(uint u) { union { uint u; float f; } v; v.u = u << 16; return v.f; }
__device__ __forceinline__ float bfh(uint u) { union { uint u; float f; } v; v.u = u & 0xffff0000u; return v.f; }

// async global->LDS, 16B per lane; LDS dest = base + lane*16 (wave-uniform base)
__device__ __forceinline__ void gl_lds16(const ushort* g, ushort* l) {
    __builtin_amdgcn_global_load_lds(
        (const __attribute__((address_space(1))) uint*)g,
        (__attribute__((address_space(3))) uint*)l, 16, 0, 0);
}

// ---------------------------------------------------------------------------
// bf16 MFMA GEMM (m97-style): C[M,N] = A[M,K] @ Bt[N,K]^T (+bias)
// BM=128, BN = 128 or 64, BK=32, 256 threads = 4 waves.
// MFMA operands swapped -> acc holds C^T: lane frow = C-row, (quad*4+i) = C-col
// so each lane owns 4 consecutive C columns -> packed stores.
//
// XCD note: mt is read from blockIdx.x with gridDim.x = 128 (== 0 mod 8).
// Column-sibling blocks (same mt, different nt) then have linear IDs
// mt + 128*nt, all congruent mod 8 -> dispatched to the SAME XCD, so the
// shared A row-panel is fetched from HBM once and L2-served to siblings.
// ---------------------------------------------------------------------------
template<int BN, bool C_F32, bool BIAS>
__global__ __launch_bounds__(256) void gemm_bt(
    const ushort* __restrict__ A, int lda,
    const ushort* __restrict__ Bt, int ldb,
    void* __restrict__ Cg, int ldc,
    const float* __restrict__ bias, int K)
{
    constexpr int NSUB = BN / 16;
    __shared__ __align__(16) ushort A_lds[128 * 32];
    __shared__ __align__(16) ushort B_lds[BN * 32];
    const int mt = blockIdx.x, nt = blockIdx.y;   // mt on fast axis (XCD-local siblings)
    const int row0 = mt * 128, col0 = nt * BN;
    const int tid = threadIdx.x;
    const int lane = tid & 63, w = tid >> 6;
    const int frow = lane & 15, quad = lane >> 4;
    const int lrow = lane >> 2, lk = (lane & 3) * 8;

    f4 acc[2][NSUB];
    #pragma unroll
    for (int mi = 0; mi < 2; ++mi)
        #pragma unroll
        for (int ni = 0; ni < NSUB; ++ni)
            acc[mi][ni] = (f4){0.f, 0.f, 0.f, 0.f};

    for (int k0 = 0; k0 < K; k0 += 32) {
        #pragma unroll
        for (int it = 0; it < 2; ++it) {
            int start = w * 16 + it * 64;
            gl_lds16(A + (size_t)(row0 + start + lrow) * lda + k0 + lk,
                     &A_lds[start * 32]);
        }
        #pragma unroll
        for (int it = 0; it < BN / 64; ++it) {
            int start = w * 16 + it * 64;
            gl_lds16(Bt + (size_t)(col0 + start + lrow) * ldb + k0 + lk,
                     &B_lds[start * 32]);
        }
        __syncthreads();

        short8 a0 = *(const short8*)&A_lds[(w * 32 + frow) * 32 + quad * 8];
        short8 a1 = *(const short8*)&A_lds[(w * 32 + 16 + frow) * 32 + quad * 8];
        #pragma unroll
        for (int ni = 0; ni < NSUB; ++ni) {
            short8 b = *(const short8*)&B_lds[(ni * 16 + frow) * 32 + quad * 8];
            acc[0][ni] = __builtin_amdgcn_mfma_f32_16x16x32_bf16(b, a0, acc[0][ni], 0, 0, 0);
            acc[1][ni] = __builtin_amdgcn_mfma_f32_16x16x32_bf16(b, a1, acc[1][ni], 0, 0, 0);
        }
        __syncthreads();
    }

    #pragma unroll
    for (int mi = 0; mi < 2; ++mi) {
        const int r = row0 + w * 32 + mi * 16 + frow;
        #pragma unroll
        for (int ni = 0; ni < NSUB; ++ni) {
            const int c = col0 + ni * 16 + quad * 4;
            f4 v = acc[mi][ni];
            if (C_F32) {
                float* C = (float*)Cg;
                if (BIAS) {
                    const float4 bv = *(const float4*)&bias[c];
                    v[0] += bv.x; v[1] += bv.y; v[2] += bv.z; v[3] += bv.w;
                }
                *(float4*)&C[(size_t)r * ldc + c] = make_float4(v[0], v[1], v[2], v[3]);
            } else {
                ushort* C = (ushort*)Cg;
                uint2 pv;
                pv.x = (uint)f2bf(v[0]) | ((uint)f2bf(v[1]) << 16);
                pv.y = (uint)f2bf(v[2]) | ((uint)f2bf(v[3]) << 16);
                *(uint2*)&C[(size_t)r * ldc + c] = pv;
            }
        }
    }
}

// ---------------------------------------------------------------------------
// prep_all: merged prep_x + prep_fuse (independent work, one launch).
// Blocks 0..255    : weight fusion (heavier; dispatched first)
//   0..127  : Wf1n[(h*256+c)][e] = sum_d Wq[e,64h+d]*Wkv[c,64h+d]
//   128..255: Wf2t[e][h*256+c]   = sum_d Wkv[c,512+64h+d]*Wout[64h+d,e]
//   Tile 64x64 (ct x et), K=64. 256 threads, 4x4 acc each.
// Blocks 256..2303 : x fp32 -> bf16, 8 elems/thread
// ---------------------------------------------------------------------------
__global__ __launch_bounds__(256) void prep_all(
    const float* __restrict__ x, ushort* __restrict__ xb,
    const float* __restrict__ Wq, const float* __restrict__ Wkv,
    const float* __restrict__ Wout,
    ushort* __restrict__ Wf1n, ushort* __restrict__ Wf2t)
{
    __shared__ float As[64][65];   // A[c][d]
    __shared__ float Bs[64][65];   // phase1: B[e][d]; phase2: B[d][e]

    if (blockIdx.x >= 256) {
        // ---- prep_x part ----
        const int i = ((blockIdx.x - 256) * 256 + threadIdx.x) * 8;
        float4 v0 = *(const float4*)&x[i];
        float4 v1 = *(const float4*)&x[i + 4];
        uint4 p;
        p.x = (uint)f2bf(v0.x) | ((uint)f2bf(v0.y) << 16);
        p.y = (uint)f2bf(v0.z) | ((uint)f2bf(v0.w) << 16);
        p.z = (uint)f2bf(v1.x) | ((uint)f2bf(v1.y) << 16);
        p.w = (uint)f2bf(v1.z) | ((uint)f2bf(v1.w) << 16);
        *(uint4*)&xb[i] = p;
        return;
    }

    const int b = blockIdx.x;
    const bool second = (b >= 128);
    const int bb = second ? b - 128 : b;
    const int h = bb >> 4, ct = (bb >> 2) & 3, et = bb & 3;
    const int t = threadIdx.x;
    const int c0 = ct * 64, e0 = et * 64;
    const int tx = t & 15, ty = t >> 4;

    // stage A[c][d]: rows of Wkv (coalesced)
    const float* Ab = Wkv + (second ? 512 : 0) + h * 64;
    #pragma unroll
    for (int it = 0; it < 4; ++it) {
        int idx = t + it * 256;
        int row = idx >> 4, col = (idx & 15) * 4;
        float4 v = *(const float4*)&Ab[(size_t)(c0 + row) * 1024 + col];
        As[row][col] = v.x; As[row][col + 1] = v.y;
        As[row][col + 2] = v.z; As[row][col + 3] = v.w;
    }
    // stage B
    #pragma unroll
    for (int it = 0; it < 4; ++it) {
        int idx = t + it * 256;
        int row = idx >> 4, col = (idx & 15) * 4;
        float4 v;
        if (second) // B[d][e] = Wout[(64h+d)*256 + e0+e]  (row=d, col=e)
            v = *(const float4*)&Wout[(size_t)(h * 64 + row) * 256 + e0 + col];
        else        // B[e][d] = Wq[(e0+e)*512 + 64h + d]  (row=e, col=d)
            v = *(const float4*)&Wq[(size_t)(e0 + row) * 512 + h * 64 + col];
        Bs[row][col] = v.x; Bs[row][col + 1] = v.y;
        Bs[row][col + 2] = v.z; Bs[row][col + 3] = v.w;
    }
    __syncthreads();

    float acc[4][4] = {};
    if (!second) {
        // C[c][e]: c = ty*4+i, e = tx*4+j
        for (int k = 0; k < 64; ++k) {
            float a[4], bb2[4];
            #pragma unroll
            for (int i = 0; i < 4; ++i) a[i] = As[ty * 4 + i][k];
            #pragma unroll
            for (int j = 0; j < 4; ++j) bb2[j] = Bs[tx * 4 + j][k];
            #pragma unroll
            for (int i = 0; i < 4; ++i)
                #pragma unroll
                for (int j = 0; j < 4; ++j)
                    acc[i][j] = fmaf(a[i], bb2[j], acc[i][j]);
        }
        #pragma unroll
        for (int i = 0; i < 4; ++i) {
            int c = c0 + ty * 4 + i;
            uint2 pv;
            pv.x = (uint)f2bf(acc[i][0]) | ((uint)f2bf(acc[i][1]) << 16);
            pv.y = (uint)f2bf(acc[i][2]) | ((uint)f2bf(acc[i][3]) << 16);
            *(uint2*)&Wf1n[(size_t)(h * 256 + c) * 256 + e0 + tx * 4] = pv;
        }
    } else {
        // C[e][c]: e = ty*4+i, c = tx*4+j
        for (int k = 0; k < 64; ++k) {
            float a[4], bb2[4];
            #pragma unroll
            for (int j = 0; j < 4; ++j) a[j] = As[tx * 4 + j][k];   // A[c][d=k]
            #pragma unroll
            for (int i = 0; i < 4; ++i) bb2[i] = Bs[k][ty * 4 + i]; // B[d=k][e]
            #pragma unroll
            for (int i = 0; i < 4; ++i)
                #pragma unroll
                for (int j = 0; j < 4; ++j)
                    acc[i][j] = fmaf(bb2[i], a[j], acc[i][j]);
        }
        #pragma unroll
        for (int i = 0; i < 4; ++i) {
            int e = e0 + ty * 4 + i;
            uint2 pv;
            pv.x = (uint)f2bf(acc[i][0]) | ((uint)f2bf(acc[i][1]) << 16);
            pv.y = (uint)f2bf(acc[i][2]) | ((uint)f2bf(acc[i][3]) << 16);
            *(uint2*)&Wf2t[(size_t)e * 2048 + h * 256 + c0 + tx * 4] = pv;
        }
    }
}

// ---------------------------------------------------------------------------
// attn: one position per 256-thread block. y (16 KB) + qk staged to LDS once;
// dots -> softmax -> ybar; ybar overwrites qk (bf16). y read from HBM once.
// ---------------------------------------------------------------------------
__global__ __launch_bounds__(256) void attn_k(
    const float* __restrict__ y, ushort* __restrict__ qk)
{
    __shared__ float ylds[16 * 260];
    __shared__ float qkf[8 * 260];
    __shared__ float part[4][8][16];
    __shared__ __align__(16) float attn_sT[16][8];
    const int p = blockIdx.x;
    const int t = threadIdx.x;
    const int w = t >> 6, lane = t & 63;
    const float* yp = y + (size_t)p * 4096;
    ushort* qkp = qk + (size_t)p * 2048;

    #pragma unroll
    for (int it = 0; it < 4; ++it) {
        int i = t + it * 256;
        float4 v = ((const float4*)yp)[i];
        int m = i >> 6, c4 = (i & 63) * 4;
        *(float4*)&ylds[m * 260 + c4] = v;
    }
    #pragma unroll
    for (int it = 0; it < 2; ++it) {
        int i = t + it * 256;
        uint2 v = ((const uint2*)qkp)[i];
        int h = i >> 6, c4 = (i & 63) * 4;
        float4 f = make_float4(bfl(v.x), bfh(v.x), bfl(v.y), bfh(v.y));
        *(float4*)&qkf[h * 260 + c4] = f;
    }
    __syncthreads();

    {
        const int m = t & 15, cs = t >> 4;
        float ps[8] = {0.f, 0.f, 0.f, 0.f, 0.f, 0.f, 0.f, 0.f};
        #pragma unroll
        for (int jj = 0; jj < 4; ++jj) {
            float4 yv = *(const float4*)&ylds[m * 260 + cs * 16 + jj * 4];
            #pragma unroll
            for (int h = 0; h < 8; ++h) {
                float4 qv = *(const float4*)&qkf[h * 260 + cs * 16 + jj * 4];
                ps[h] += yv.x * qv.x + yv.y * qv.y + yv.z * qv.z + yv.w * qv.w;
            }
        }
        #pragma unroll
        for (int h = 0; h < 8; ++h) {
            float s = ps[h];
            s += __shfl_xor(s, 16);
            s += __shfl_xor(s, 32);
            if (lane < 16) part[w][h][m] = s;
        }
    }
    __syncthreads();

    if (t < 128) {
        const int h = t >> 4, mm = t & 15;
        float d = (part[0][h][mm] + part[1][h][mm] + part[2][h][mm] + part[3][h][mm]) * ATT_SCALE;
        float mx = d;
        #pragma unroll
        for (int off = 8; off >= 1; off >>= 1) mx = fmaxf(mx, __shfl_xor(mx, off));
        float e = __expf(d - mx);
        float sm = e;
        #pragma unroll
        for (int off = 8; off >= 1; off >>= 1) sm += __shfl_xor(sm, off);
        attn_sT[mm][h] = e / sm;
    }
    __syncthreads();

    {
        float acc[8] = {0.f, 0.f, 0.f, 0.f, 0.f, 0.f, 0.f, 0.f};
        #pragma unroll
        for (int mm = 0; mm < 16; ++mm) {
            float yv = ylds[mm * 260 + t];
            float4 a0 = *(const float4*)&attn_sT[mm][0];
            float4 a1 = *(const float4*)&attn_sT[mm][4];
            acc[0] = fmaf(a0.x, yv, acc[0]);
            acc[1] = fmaf(a0.y, yv, acc[1]);
            acc[2] = fmaf(a0.z, yv, acc[2]);
            acc[3] = fmaf(a0.w, yv, acc[3]);
            acc[4] = fmaf(a1.x, yv, acc[4]);
            acc[5] = fmaf(a1.y, yv, acc[5]);
            acc[6] = fmaf(a1.z, yv, acc[6]);
            acc[7] = fmaf(a1.w, yv, acc[7]);
        }
        #pragma unroll
        for (int h = 0; h < 8; ++h) qkp[h * 256 + t] = f2bf(acc[h]);
    }
}

extern "C" void kernel_launch(void* const* d_in, const int* in_sizes, int n_in,
                              void* d_out, int out_size, void* d_ws, size_t ws_size,
                              hipStream_t stream)
{
    (void)in_sizes; (void)n_in; (void)out_size; (void)ws_size;
    const float* x     = (const float*)d_in[0];
    const float* y     = (const float*)d_in[1];
    const float* W_q   = (const float*)d_in[2];
    const float* W_kv  = (const float*)d_in[3];
    const float* W_out = (const float*)d_in[4];
    const float* b_out = (const float*)d_in[5];
    float* out = (float*)d_out;

    ushort* qk   = (ushort*)d_ws;
    ushort* xb   = qk + (size_t)NPOS * 2048;
    ushort* Wf1n = xb + (size_t)NPOS * 256;
    ushort* Wf2t = Wf1n + 2048 * 256;

    dim3 blk(256);

    // merged prep: blocks 0..255 weight-fuse, 256..2303 x->bf16
    prep_all<<<dim3(2304), blk, 0, stream>>>(x, xb, W_q, W_kv, W_out, Wf1n, Wf2t);

    // K1: qk = xb @ Wf1n^T   [16384,256] x [256,2048] -> bf16
    // grid (mt=128, nt=16): column-siblings share an XCD -> A panel L2-reused
    gemm_bt<128, false, false><<<dim3(128, 16), blk, 0, stream>>>(
        xb, 256, Wf1n, 256, qk, 2048, nullptr, 256);

    // K2: attention in place over qk
    attn_k<<<dim3(NPOS), blk, 0, stream>>>(y, qk);

    // K3: out = ybar @ Wf2t^T + b_out   [16384,2048] x [2048,256] -> fp32
    // grid (mt=128, nt=4): the 4 column-siblings of each qk row-panel land on
    // one XCD -> qk fetched from HBM ~once instead of ~4x.
    gemm_bt<64, true, true><<<dim3(128, 4), blk, 0, stream>>>(
        qk, 2048, Wf2t, 2048, out, 256, b_out, 2048);
}

// Round 2
// 465.661 us; speedup vs baseline: 1.0470x; 1.0382x over previous
//
#include <hip/hip_runtime.h>
#include <cmath>

#define NPOS 16384
#define ATT_SCALE 0.125f

typedef float f4 __attribute__((ext_vector_type(4)));
typedef short short8 __attribute__((ext_vector_type(8)));
typedef unsigned int uint;
typedef unsigned short ushort;

__device__ __forceinline__ ushort f2bf(float f) {
    union { float f; uint u; } v; v.f = f;
    uint r = v.u + 0x7fffu + ((v.u >> 16) & 1u);
    return (ushort)(r >> 16);
}
__device__ __forceinline__ float bfl(uint u) { union { uint u; float f; } v; v.u = u << 16; return v.f; }
__device__ __forceinline__ float bfh(uint u) { union { uint u; float f; } v; v.u = u & 0xffff0000u; return v.f; }

// async global->LDS, 16B per lane; LDS dest = base + lane*16 (wave-uniform base)
__device__ __forceinline__ void gl_lds16(const ushort* g, ushort* l) {
    __builtin_amdgcn_global_load_lds(
        (const __attribute__((address_space(1))) uint*)g,
        (__attribute__((address_space(3))) uint*)l, 16, 0, 0);
}

// ---------------------------------------------------------------------------
// bf16 MFMA GEMM v2: C[M,N] = A[M,K] @ Bt[N,K]^T (+bias)
// BM=128, BN = 128 or 64, BK=64, 256 threads = 4 waves in a 2x2 grid:
//   wave w owns sub-tile rows (w>>1)*64..+63, cols (w&1)*(BN/2)..  -> A and B
//   each re-read by only 2 waves (vs B x4 in the old 1x4 mapping): per-step
//   LDS traffic drops 20%, and BK=64 halves barrier+vmcnt-drain events.
// Rows are 128 B at BK=64 -> 16-way bank conflict if linear, so chunks are
// XOR-swizzled (chunk ^= row&7) on BOTH sides: global source address is
// pre-swizzled (global_load_lds dest must stay linear), and frag ds_reads
// apply the same XOR. Self-inverse: LDS[r][c] = G[r][c^(r&7)].
// MFMA operands swapped -> acc holds C^T: lane frow = C-row, quad*4+i = C-col.
// XCD note: mt on blockIdx.x with gridDim.x = 128 (0 mod 8) keeps
// column-sibling blocks on one XCD -> A row-panel L2-reused.
// ---------------------------------------------------------------------------
template<int BN, bool C_F32, bool BIAS>
__global__ __launch_bounds__(256) void gemm_bt(
    const ushort* __restrict__ A, int lda,
    const ushort* __restrict__ Bt, int ldb,
    void* __restrict__ Cg, int ldc,
    const float* __restrict__ bias, int K)
{
    constexpr int NI = BN / 32;              // n-frags per wave (2x2 mapping)
    __shared__ __align__(16) ushort A_lds[128 * 64];
    __shared__ __align__(16) ushort B_lds[BN * 64];
    const int mt = blockIdx.x, nt = blockIdx.y;
    const int row0 = mt * 128, col0 = nt * BN;
    const int tid = threadIdx.x;
    const int lane = tid & 63, w = tid >> 6;
    const int frow = lane & 15, quad = lane >> 4;
    const int wr = (w >> 1) * 64, wc = (w & 1) * (BN / 2);
    // staging: each wave-issue moves 8 rows x 128 B; lane fills row sr+(lane>>3),
    // LDS chunk lane&7; global source chunk = (lane&7)^(lane>>3) (row&7 == lane>>3)
    const int srow = lane >> 3;
    const int gch = ((lane & 7) ^ (lane >> 3)) * 8;

    f4 acc[4][NI];
    #pragma unroll
    for (int mi = 0; mi < 4; ++mi)
        #pragma unroll
        for (int ni = 0; ni < NI; ++ni)
            acc[mi][ni] = (f4){0.f, 0.f, 0.f, 0.f};

    for (int k0 = 0; k0 < K; k0 += 64) {
        #pragma unroll
        for (int it = 0; it < 4; ++it) {          // A: 128 rows / (4 waves * 8)
            int sr = (it * 4 + w) * 8;
            gl_lds16(A + (size_t)(row0 + sr + srow) * lda + k0 + gch,
                     &A_lds[sr * 64]);
        }
        #pragma unroll
        for (int it = 0; it < BN / 32; ++it) {    // B: BN rows
            int sr = (it * 4 + w) * 8;
            gl_lds16(Bt + (size_t)(col0 + sr + srow) * ldb + k0 + gch,
                     &B_lds[sr * 64]);
        }
        __syncthreads();

        #pragma unroll
        for (int kk = 0; kk < 2; ++kk) {
            const int ko = (((kk * 4 + quad) ^ (frow & 7)) << 3);  // swizzled k-chunk
            short8 av[4];
            #pragma unroll
            for (int mi = 0; mi < 4; ++mi)
                av[mi] = *(const short8*)&A_lds[(wr + mi * 16 + frow) * 64 + ko];
            #pragma unroll
            for (int ni = 0; ni < NI; ++ni) {
                short8 bv = *(const short8*)&B_lds[(wc + ni * 16 + frow) * 64 + ko];
                #pragma unroll
                for (int mi = 0; mi < 4; ++mi)
                    acc[mi][ni] = __builtin_amdgcn_mfma_f32_16x16x32_bf16(bv, av[mi], acc[mi][ni], 0, 0, 0);
            }
        }
        __syncthreads();
    }

    #pragma unroll
    for (int mi = 0; mi < 4; ++mi) {
        const int r = row0 + wr + mi * 16 + frow;
        #pragma unroll
        for (int ni = 0; ni < NI; ++ni) {
            const int c = col0 + wc + ni * 16 + quad * 4;
            f4 v = acc[mi][ni];
            if (C_F32) {
                float* C = (float*)Cg;
                if (BIAS) {
                    const float4 bv = *(const float4*)&bias[c];
                    v[0] += bv.x; v[1] += bv.y; v[2] += bv.z; v[3] += bv.w;
                }
                *(float4*)&C[(size_t)r * ldc + c] = make_float4(v[0], v[1], v[2], v[3]);
            } else {
                ushort* C = (ushort*)Cg;
                uint2 pv;
                pv.x = (uint)f2bf(v[0]) | ((uint)f2bf(v[1]) << 16);
                pv.y = (uint)f2bf(v[2]) | ((uint)f2bf(v[3]) << 16);
                *(uint2*)&C[(size_t)r * ldc + c] = pv;
            }
        }
    }
}

// ---------------------------------------------------------------------------
// prep_all: merged prep_x + prep_fuse (independent work, one launch).
// Blocks 0..255    : weight fusion
//   0..127  : Wf1n[(h*256+c)][e] = sum_d Wq[e,64h+d]*Wkv[c,64h+d]
//   128..255: Wf2t[e][h*256+c]   = sum_d Wkv[c,512+64h+d]*Wout[64h+d,e]
// Blocks 256..2303 : x fp32 -> bf16, 8 elems/thread
// ---------------------------------------------------------------------------
__global__ __launch_bounds__(256) void prep_all(
    const float* __restrict__ x, ushort* __restrict__ xb,
    const float* __restrict__ Wq, const float* __restrict__ Wkv,
    const float* __restrict__ Wout,
    ushort* __restrict__ Wf1n, ushort* __restrict__ Wf2t)
{
    __shared__ float As[64][65];   // A[c][d]
    __shared__ float Bs[64][65];   // phase1: B[e][d]; phase2: B[d][e]

    if (blockIdx.x >= 256) {
        const int i = ((blockIdx.x - 256) * 256 + threadIdx.x) * 8;
        float4 v0 = *(const float4*)&x[i];
        float4 v1 = *(const float4*)&x[i + 4];
        uint4 p;
        p.x = (uint)f2bf(v0.x) | ((uint)f2bf(v0.y) << 16);
        p.y = (uint)f2bf(v0.z) | ((uint)f2bf(v0.w) << 16);
        p.z = (uint)f2bf(v1.x) | ((uint)f2bf(v1.y) << 16);
        p.w = (uint)f2bf(v1.z) | ((uint)f2bf(v1.w) << 16);
        *(uint4*)&xb[i] = p;
        return;
    }

    const int b = blockIdx.x;
    const bool second = (b >= 128);
    const int bb = second ? b - 128 : b;
    const int h = bb >> 4, ct = (bb >> 2) & 3, et = bb & 3;
    const int t = threadIdx.x;
    const int c0 = ct * 64, e0 = et * 64;
    const int tx = t & 15, ty = t >> 4;

    const float* Ab = Wkv + (second ? 512 : 0) + h * 64;
    #pragma unroll
    for (int it = 0; it < 4; ++it) {
        int idx = t + it * 256;
        int row = idx >> 4, col = (idx & 15) * 4;
        float4 v = *(const float4*)&Ab[(size_t)(c0 + row) * 1024 + col];
        As[row][col] = v.x; As[row][col + 1] = v.y;
        As[row][col + 2] = v.z; As[row][col + 3] = v.w;
    }
    #pragma unroll
    for (int it = 0; it < 4; ++it) {
        int idx = t + it * 256;
        int row = idx >> 4, col = (idx & 15) * 4;
        float4 v;
        if (second) // B[d][e] = Wout[(64h+d)*256 + e0+e]
            v = *(const float4*)&Wout[(size_t)(h * 64 + row) * 256 + e0 + col];
        else        // B[e][d] = Wq[(e0+e)*512 + 64h + d]
            v = *(const float4*)&Wq[(size_t)(e0 + row) * 512 + h * 64 + col];
        Bs[row][col] = v.x; Bs[row][col + 1] = v.y;
        Bs[row][col + 2] = v.z; Bs[row][col + 3] = v.w;
    }
    __syncthreads();

    float acc[4][4] = {};
    if (!second) {
        for (int k = 0; k < 64; ++k) {
            float a[4], bb2[4];
            #pragma unroll
            for (int i = 0; i < 4; ++i) a[i] = As[ty * 4 + i][k];
            #pragma unroll
            for (int j = 0; j < 4; ++j) bb2[j] = Bs[tx * 4 + j][k];
            #pragma unroll
            for (int i = 0; i < 4; ++i)
                #pragma unroll
                for (int j = 0; j < 4; ++j)
                    acc[i][j] = fmaf(a[i], bb2[j], acc[i][j]);
        }
        #pragma unroll
        for (int i = 0; i < 4; ++i) {
            int c = c0 + ty * 4 + i;
            uint2 pv;
            pv.x = (uint)f2bf(acc[i][0]) | ((uint)f2bf(acc[i][1]) << 16);
            pv.y = (uint)f2bf(acc[i][2]) | ((uint)f2bf(acc[i][3]) << 16);
            *(uint2*)&Wf1n[(size_t)(h * 256 + c) * 256 + e0 + tx * 4] = pv;
        }
    } else {
        for (int k = 0; k < 64; ++k) {
            float a[4], bb2[4];
            #pragma unroll
            for (int j = 0; j < 4; ++j) a[j] = As[tx * 4 + j][k];
            #pragma unroll
            for (int i = 0; i < 4; ++i) bb2[i] = Bs[k][ty * 4 + i];
            #pragma unroll
            for (int i = 0; i < 4; ++i)
                #pragma unroll
                for (int j = 0; j < 4; ++j)
                    acc[i][j] = fmaf(bb2[i], a[j], acc[i][j]);
        }
        #pragma unroll
        for (int i = 0; i < 4; ++i) {
            int e = e0 + ty * 4 + i;
            uint2 pv;
            pv.x = (uint)f2bf(acc[i][0]) | ((uint)f2bf(acc[i][1]) << 16);
            pv.y = (uint)f2bf(acc[i][2]) | ((uint)f2bf(acc[i][3]) << 16);
            *(uint2*)&Wf2t[(size_t)e * 2048 + h * 256 + c0 + tx * 4] = pv;
        }
    }
}

// ---------------------------------------------------------------------------
// attn: one position per 256-thread block. y (16 KB) + qk staged to LDS once;
// dots -> softmax -> ybar; ybar overwrites qk (bf16). y read from HBM once.
// ---------------------------------------------------------------------------
__global__ __launch_bounds__(256) void attn_k(
    const float* __restrict__ y, ushort* __restrict__ qk)
{
    __shared__ float ylds[16 * 260];
    __shared__ float qkf[8 * 260];
    __shared__ float part[4][8][16];
    __shared__ __align__(16) float attn_sT[16][8];
    const int p = blockIdx.x;
    const int t = threadIdx.x;
    const int w = t >> 6, lane = t & 63;
    const float* yp = y + (size_t)p * 4096;
    ushort* qkp = qk + (size_t)p * 2048;

    #pragma unroll
    for (int it = 0; it < 4; ++it) {
        int i = t + it * 256;
        float4 v = ((const float4*)yp)[i];
        int m = i >> 6, c4 = (i & 63) * 4;
        *(float4*)&ylds[m * 260 + c4] = v;
    }
    #pragma unroll
    for (int it = 0; it < 2; ++it) {
        int i = t + it * 256;
        uint2 v = ((const uint2*)qkp)[i];
        int h = i >> 6, c4 = (i & 63) * 4;
        float4 f = make_float4(bfl(v.x), bfh(v.x), bfl(v.y), bfh(v.y));
        *(float4*)&qkf[h * 260 + c4] = f;
    }
    __syncthreads();

    {
        const int m = t & 15, cs = t >> 4;
        float ps[8] = {0.f, 0.f, 0.f, 0.f, 0.f, 0.f, 0.f, 0.f};
        #pragma unroll
        for (int jj = 0; jj < 4; ++jj) {
            float4 yv = *(const float4*)&ylds[m * 260 + cs * 16 + jj * 4];
            #pragma unroll
            for (int h = 0; h < 8; ++h) {
                float4 qv = *(const float4*)&qkf[h * 260 + cs * 16 + jj * 4];
                ps[h] += yv.x * qv.x + yv.y * qv.y + yv.z * qv.z + yv.w * qv.w;
            }
        }
        #pragma unroll
        for (int h = 0; h < 8; ++h) {
            float s = ps[h];
            s += __shfl_xor(s, 16);
            s += __shfl_xor(s, 32);
            if (lane < 16) part[w][h][m] = s;
        }
    }
    __syncthreads();

    if (t < 128) {
        const int h = t >> 4, mm = t & 15;
        float d = (part[0][h][mm] + part[1][h][mm] + part[2][h][mm] + part[3][h][mm]) * ATT_SCALE;
        float mx = d;
        #pragma unroll
        for (int off = 8; off >= 1; off >>= 1) mx = fmaxf(mx, __shfl_xor(mx, off));
        float e = __expf(d - mx);
        float sm = e;
        #pragma unroll
        for (int off = 8; off >= 1; off >>= 1) sm += __shfl_xor(sm, off);
        attn_sT[mm][h] = e / sm;
    }
    __syncthreads();

    {
        float acc[8] = {0.f, 0.f, 0.f, 0.f, 0.f, 0.f, 0.f, 0.f};
        #pragma unroll
        for (int mm = 0; mm < 16; ++mm) {
            float yv = ylds[mm * 260 + t];
            float4 a0 = *(const float4*)&attn_sT[mm][0];
            float4 a1 = *(const float4*)&attn_sT[mm][4];
            acc[0] = fmaf(a0.x, yv, acc[0]);
            acc[1] = fmaf(a0.y, yv, acc[1]);
            acc[2] = fmaf(a0.z, yv, acc[2]);
            acc[3] = fmaf(a0.w, yv, acc[3]);
            acc[4] = fmaf(a1.x, yv, acc[4]);
            acc[5] = fmaf(a1.y, yv, acc[5]);
            acc[6] = fmaf(a1.z, yv, acc[6]);
            acc[7] = fmaf(a1.w, yv, acc[7]);
        }
        #pragma unroll
        for (int h = 0; h < 8; ++h) qkp[h * 256 + t] = f2bf(acc[h]);
    }
}

extern "C" void kernel_launch(void* const* d_in, const int* in_sizes, int n_in,
                              void* d_out, int out_size, void* d_ws, size_t ws_size,
                              hipStream_t stream)
{
    (void)in_sizes; (void)n_in; (void)out_size; (void)ws_size;
    const float* x     = (const float*)d_in[0];
    const float* y     = (const float*)d_in[1];
    const float* W_q   = (const float*)d_in[2];
    const float* W_kv  = (const float*)d_in[3];
    const float* W_out = (const float*)d_in[4];
    const float* b_out = (const float*)d_in[5];
    float* out = (float*)d_out;

    ushort* qk   = (ushort*)d_ws;
    ushort* xb   = qk + (size_t)NPOS * 2048;
    ushort* Wf1n = xb + (size_t)NPOS * 256;
    ushort* Wf2t = Wf1n + 2048 * 256;

    dim3 blk(256);

    // merged prep: blocks 0..255 weight-fuse, 256..2303 x->bf16
    prep_all<<<dim3(2304), blk, 0, stream>>>(x, xb, W_q, W_kv, W_out, Wf1n, Wf2t);

    // K1: qk = xb @ Wf1n^T   [16384,256] x [256,2048] -> bf16
    gemm_bt<128, false, false><<<dim3(128, 16), blk, 0, stream>>>(
        xb, 256, Wf1n, 256, qk, 2048, nullptr, 256);

    // K2: attention in place over qk
    attn_k<<<dim3(NPOS), blk, 0, stream>>>(y, qk);

    // K3: out = ybar @ Wf2t^T + b_out   [16384,2048] x [2048,256] -> fp32
    gemm_bt<64, true, true><<<dim3(128, 4), blk, 0, stream>>>(
        qk, 2048, Wf2t, 2048, out, 256, b_out, 2048);
}